// Round 4
// baseline (1430.520 us; speedup 1.0000x reference)
//
#include <hip/hip_runtime.h>

#define NN 50000          // nodes
#define NE 800000         // edges (without self loops)
#define NT (NE + NN)      // edges + self loops
#define SLICE_ST ((size_t)NN * 16)   // floats per 16-wide feature slice

// ---------------- graph preprocessing ----------------

__global__ void zero_deg_kernel(int* deg) {
  int v = blockIdx.x * 256 + threadIdx.x;
  if (v < NN) deg[v] = 0;
}

__global__ void count_deg_kernel(const int* __restrict__ edst, int* __restrict__ deg) {
  int i = blockIdx.x * 256 + threadIdx.x;
  if (i < NE) atomicAdd(&deg[edst[i]], 1);
}

__global__ void dinv_kernel(const int* __restrict__ deg, float* __restrict__ dinv) {
  int v = blockIdx.x * 256 + threadIdx.x;
  if (v < NN) dinv[v] = rsqrtf((float)(deg[v] + 1));   // +1 self loop
}

// inclusive scan of counts (deg+1) in chunks of 1024
__global__ __launch_bounds__(1024) void scan1_kernel(const int* __restrict__ deg,
                                                     int* __restrict__ incl,
                                                     int* __restrict__ bsum) {
  __shared__ int sd[1024];
  int gid = blockIdx.x * 1024 + threadIdx.x;
  int v = (gid < NN) ? (deg[gid] + 1) : 0;
  sd[threadIdx.x] = v;
  __syncthreads();
  for (int off = 1; off < 1024; off <<= 1) {
    int t = (threadIdx.x >= off) ? sd[threadIdx.x - off] : 0;
    __syncthreads();
    sd[threadIdx.x] += t;
    __syncthreads();
  }
  if (gid < NN) incl[gid] = sd[threadIdx.x];
  if (threadIdx.x == 1023) bsum[blockIdx.x] = sd[1023];
}

__global__ void scan2_kernel(int* bsum, int nb) {
  if (threadIdx.x == 0 && blockIdx.x == 0) {
    int run = 0;
    for (int i = 0; i < nb; ++i) { int t = bsum[i]; bsum[i] = run; run += t; }
  }
}

__global__ void scan3_kernel(const int* __restrict__ deg, const int* __restrict__ incl,
                             const int* __restrict__ bsum, int* __restrict__ offs,
                             int* __restrict__ cursor) {
  int v = blockIdx.x * 256 + threadIdx.x;
  if (v >= NN) return;
  int o = bsum[v >> 10] + incl[v] - (deg[v] + 1);
  offs[v] = o;
  cursor[v] = o;
  if (v == 0) offs[NN] = NT;
}

__global__ void fill_kernel(const int* __restrict__ esrc, const int* __restrict__ edst,
                            const float* __restrict__ dinv, int* __restrict__ cursor,
                            int* __restrict__ csrc, float* __restrict__ cw) {
  int i = blockIdx.x * 256 + threadIdx.x;
  if (i >= NT) return;
  int s, d;
  if (i < NE) { s = esrc[i]; d = edst[i]; }
  else        { s = d = i - NE; }           // self loop
  int p = atomicAdd(&cursor[d], 1);
  csrc[p] = s;
  cw[p] = dinv[s] * dinv[d];
}

// ---------------- dense GEMM: out = A[M,K] @ W[K,COLS] + bias ----------------
// 256 threads, tile 64 rows x COLS, K-chunk 32. Thread = 4 rows x CPT cols.
// tc = tid/16 -> ws reads are 16-lane broadcasts, conflict-free.
// xs stride 33 -> bank (4tr+r+k)%32 -> 2-way (free).
// A_SLICED: A stored as 16-wide feature slices [k/16][row][k%16].
// OUT_NSL: 0 = row-major out; else write to OUT_NSL slices of 16.

template <int K, int COLS, bool A_SLICED, int OUT_NSL>
__global__ __launch_bounds__(256) void gemm_bias_kernel(const float* __restrict__ A,
                                                        const float* __restrict__ W,
                                                        const float* __restrict__ bias,
                                                        float* __restrict__ out, int M) {
  constexpr int CPT = COLS / 16;  // 8 or 4
  __shared__ float xs[64][33];
  __shared__ float ws[32][COLS];

  int tid = threadIdx.x;
  int tc = tid >> 4;              // 0..15 col group (wave-local 0..3)
  int tr = tid & 15;              // 0..15 row group
  int row0 = blockIdx.x * 64;

  float acc[4][CPT] = {};

  for (int kc = 0; kc < K; kc += 32) {
    // stage xs: 64 rows x 32 k = 512 float4 loads
    for (int i = tid; i < 512; i += 256) {
      int r = i >> 3, k4 = i & 7;
      int row = row0 + r;
      float4 v = make_float4(0.f, 0.f, 0.f, 0.f);
      if (row < M) {
        int kk = kc + k4 * 4;
        const float* p;
        if (A_SLICED) p = A + (size_t)(kk >> 4) * SLICE_ST + (size_t)row * 16 + (kk & 15);
        else          p = A + (size_t)row * K + kk;
        v = *reinterpret_cast<const float4*>(p);
      }
      xs[r][k4 * 4 + 0] = v.x;
      xs[r][k4 * 4 + 1] = v.y;
      xs[r][k4 * 4 + 2] = v.z;
      xs[r][k4 * 4 + 3] = v.w;
    }
    // stage ws: 32 x COLS
    for (int i = tid; i < 32 * COLS / 4; i += 256) {
      int k = i / (COLS / 4), c4 = i % (COLS / 4);
      *reinterpret_cast<float4*>(&ws[k][c4 * 4]) =
          *reinterpret_cast<const float4*>(&W[(size_t)(kc + k) * COLS + c4 * 4]);
    }
    __syncthreads();
#pragma unroll
    for (int k = 0; k < 32; ++k) {
      float xv[4];
#pragma unroll
      for (int r = 0; r < 4; ++r) xv[r] = xs[tr * 4 + r][k];
#pragma unroll
      for (int j4 = 0; j4 < CPT / 4; ++j4) {
        float4 wv = *reinterpret_cast<const float4*>(&ws[k][tc * CPT + j4 * 4]);
#pragma unroll
        for (int r = 0; r < 4; ++r) {
          acc[r][j4 * 4 + 0] += xv[r] * wv.x;
          acc[r][j4 * 4 + 1] += xv[r] * wv.y;
          acc[r][j4 * 4 + 2] += xv[r] * wv.z;
          acc[r][j4 * 4 + 3] += xv[r] * wv.w;
        }
      }
    }
    __syncthreads();
  }

#pragma unroll
  for (int r = 0; r < 4; ++r) {
    int row = row0 + tr * 4 + r;
    if (row < M) {
#pragma unroll
      for (int j4 = 0; j4 < CPT / 4; ++j4) {
        int c = tc * CPT + j4 * 4;
        float4 bv = *reinterpret_cast<const float4*>(&bias[c]);
        float4 o;
        o.x = acc[r][j4 * 4 + 0] + bv.x;
        o.y = acc[r][j4 * 4 + 1] + bv.y;
        o.z = acc[r][j4 * 4 + 2] + bv.z;
        o.w = acc[r][j4 * 4 + 3] + bv.w;
        float* p;
        if (OUT_NSL == 0) p = out + (size_t)row * COLS + c;
        else              p = out + (size_t)(c >> 4) * SLICE_ST + (size_t)row * 16 + (c & 15);
        *reinterpret_cast<float4*>(p) = o;
      }
    }
  }
}

// ---------------- XCD-sliced propagation ----------------
// h stored slice-major: NSL slices of [NN][16] floats. blockIdx%8 selects the
// (slice, node-half) pair so that (with round-robin block->XCD dispatch) each
// XCD gathers from one 3.2MB slice table that fits its private 4MB L2.
// 4 threads/node, float4 gathers; edge metadata via nontemporal loads.

template <int NSL, bool APPNP, bool OUT_NORMAL>
__global__ __launch_bounds__(256) void propS_kernel(const float* __restrict__ hin,
                                                    const float* __restrict__ h0,
                                                    float* __restrict__ out,
                                                    const int* __restrict__ offs,
                                                    const int* __restrict__ csrc,
                                                    const float* __restrict__ cw) {
  constexpr int NHALF = 8 / NSL;                  // node partitions per slice
  constexpr int SPAN = (NN + NHALF - 1) / NHALF;  // nodes per partition
  int s8 = blockIdx.x & 7;
  int slice = s8 % NSL;
  int half = s8 / NSL;
  int node0 = half * SPAN;
  int node = node0 + (int)(blockIdx.x >> 3) * 64 + (threadIdx.x >> 2);
  int nend = (NN < node0 + SPAN) ? NN : (node0 + SPAN);
  if (node >= nend) return;
  int f4 = (threadIdx.x & 3) * 4;

  const float* __restrict__ hs = hin + (size_t)slice * SLICE_ST + f4;
  int e = offs[node];
  int e1 = offs[node + 1];
  float ax = 0.f, ay = 0.f, az = 0.f, aw = 0.f;
  for (; e + 3 < e1; e += 4) {
    int s0 = __builtin_nontemporal_load(csrc + e + 0);
    int s1 = __builtin_nontemporal_load(csrc + e + 1);
    int s2 = __builtin_nontemporal_load(csrc + e + 2);
    int s3 = __builtin_nontemporal_load(csrc + e + 3);
    float w0 = __builtin_nontemporal_load(cw + e + 0);
    float w1 = __builtin_nontemporal_load(cw + e + 1);
    float w2 = __builtin_nontemporal_load(cw + e + 2);
    float w3 = __builtin_nontemporal_load(cw + e + 3);
    float4 v0 = *reinterpret_cast<const float4*>(hs + (size_t)s0 * 16);
    float4 v1 = *reinterpret_cast<const float4*>(hs + (size_t)s1 * 16);
    float4 v2 = *reinterpret_cast<const float4*>(hs + (size_t)s2 * 16);
    float4 v3 = *reinterpret_cast<const float4*>(hs + (size_t)s3 * 16);
    ax += w0 * v0.x + w1 * v1.x + w2 * v2.x + w3 * v3.x;
    ay += w0 * v0.y + w1 * v1.y + w2 * v2.y + w3 * v3.y;
    az += w0 * v0.z + w1 * v1.z + w2 * v2.z + w3 * v3.z;
    aw += w0 * v0.w + w1 * v1.w + w2 * v2.w + w3 * v3.w;
  }
  for (; e < e1; ++e) {
    int s = __builtin_nontemporal_load(csrc + e);
    float wv = __builtin_nontemporal_load(cw + e);
    float4 v = *reinterpret_cast<const float4*>(hs + (size_t)s * 16);
    ax += wv * v.x; ay += wv * v.y; az += wv * v.z; aw += wv * v.w;
  }
  if (APPNP) {
    float4 z = *reinterpret_cast<const float4*>(
        h0 + (size_t)slice * SLICE_ST + (size_t)node * 16 + f4);
    ax = 0.9f * ax + 0.1f * z.x;
    ay = 0.9f * ay + 0.1f * z.y;
    az = 0.9f * az + 0.1f * z.z;
    aw = 0.9f * aw + 0.1f * z.w;
  }
  float4 o = make_float4(ax, ay, az, aw);
  float* p;
  if (OUT_NORMAL) p = out + (size_t)node * (NSL * 16) + slice * 16 + f4;
  else            p = out + (size_t)slice * SLICE_ST + (size_t)node * 16 + f4;
  *reinterpret_cast<float4*>(p) = o;
}

// ---------------- launch ----------------

extern "C" void kernel_launch(void* const* d_in, const int* in_sizes, int n_in,
                              void* d_out, int out_size, void* d_ws, size_t ws_size,
                              hipStream_t stream) {
  const float* x    = (const float*)d_in[0];   // [50000,256]
  const int*   eidx = (const int*)d_in[1];     // [2,800000]
  const float* W1   = (const float*)d_in[2];   // [256,128]
  const float* b1   = (const float*)d_in[3];   // [128]
  const float* W3   = (const float*)d_in[4];   // [128,64]
  const float* b3   = (const float*)d_in[5];   // [64]
  float* outp = (float*)d_out;                 // [50000,64]

  const int* esrc = eidx;
  const int* edst = eidx + NE;

  // workspace layout (256B aligned)
  char* w = (char*)d_ws;
  size_t off = 0;
  auto take = [&](size_t bytes) {
    void* p = w + off;
    off = (off + bytes + 255) & ~(size_t)255;
    return p;
  };
  int*   deg    = (int*)take(NN * 4);
  float* dinv   = (float*)take(NN * 4);
  int*   incl   = (int*)take(NN * 4);
  int*   offs   = (int*)take((NN + 1) * 4);
  int*   cursor = (int*)take(NN * 4);
  int*   bsum   = (int*)take(64 * 4);
  int*   csrc   = (int*)take((size_t)NT * 4);
  float* cwv    = (float*)take((size_t)NT * 4);
  float* h0b    = (float*)take((size_t)NN * 128 * 4);   // sliced-8
  float* ping   = (float*)take((size_t)NN * 128 * 4);   // sliced-8
  float* pong   = (float*)take((size_t)NN * 128 * 4);   // sliced-8
  (void)ws_size; (void)in_sizes; (void)n_in; (void)out_size;

  const int nblkN = (NN + 255) / 256;          // 196
  const int nblkE = (NE + 255) / 256;          // 3125
  const int nblkT = (NT + 255) / 256;          // 3321
  const int nbScan = (NN + 1023) / 1024;       // 49

  // --- graph norm + CSR build ---
  zero_deg_kernel<<<nblkN, 256, 0, stream>>>(deg);
  count_deg_kernel<<<nblkE, 256, 0, stream>>>(edst, deg);
  dinv_kernel<<<nblkN, 256, 0, stream>>>(deg, dinv);
  scan1_kernel<<<nbScan, 1024, 0, stream>>>(deg, incl, bsum);
  scan2_kernel<<<1, 64, 0, stream>>>(bsum, nbScan);
  scan3_kernel<<<nblkN, 256, 0, stream>>>(deg, incl, bsum, offs, cursor);
  fill_kernel<<<nblkT, 256, 0, stream>>>(esrc, edst, dinv, cursor, csrc, cwv);

  const int gblk = (NN + 63) / 64;             // 782
  const int pblk8 = 8 * ((NN + 63) / 64);      // 6256  (slices x node chunks)
  const int pblk4 = 8 * ((25000 + 63) / 64);   // 3128

  // --- GCNConv1: h0 = prop(x @ W1 + b1) ---
  gemm_bias_kernel<256, 128, false, 8><<<gblk, 256, 0, stream>>>(x, W1, b1, ping, NN);
  propS_kernel<8, false, false><<<pblk8, 256, 0, stream>>>(ping, nullptr, h0b, offs, csrc, cwv);

  // --- APPNP: 10 x h = 0.9*prop(h) + 0.1*h0 ---
  const float* hc = h0b;
  float* bufs[2] = {ping, pong};
  for (int it = 0; it < 10; ++it) {
    float* hn = bufs[it & 1];
    propS_kernel<8, true, false><<<pblk8, 256, 0, stream>>>(hc, h0b, hn, offs, csrc, cwv);
    hc = hn;
  }
  // hc == pong after 10 iters; ping is free
  float* t64 = ping;

  // --- GCNConv2: out = prop(h @ W3 + b3) ---
  gemm_bias_kernel<128, 64, true, 4><<<gblk, 256, 0, stream>>>(hc, W3, b3, t64, NN);
  propS_kernel<4, false, true><<<pblk4, 256, 0, stream>>>(t64, nullptr, outp, offs, csrc, cwv);
}

// Round 5
// 890.396 us; speedup vs baseline: 1.6066x; 1.6066x over previous
//
#include <hip/hip_runtime.h>

#define NN 50000          // nodes
#define NE 800000         // edges (without self loops)
#define NT (NE + NN)      // edges + self loops

// ---------------- graph preprocessing ----------------

__global__ void zero_deg_kernel(int* deg) {
  int v = blockIdx.x * 256 + threadIdx.x;
  if (v < NN) deg[v] = 0;
}

__global__ void count_deg_kernel(const int* __restrict__ edst, int* __restrict__ deg) {
  int i = blockIdx.x * 256 + threadIdx.x;
  if (i < NE) atomicAdd(&deg[edst[i]], 1);
}

__global__ void dinv_kernel(const int* __restrict__ deg, float* __restrict__ dinv) {
  int v = blockIdx.x * 256 + threadIdx.x;
  if (v < NN) dinv[v] = rsqrtf((float)(deg[v] + 1));   // +1 self loop
}

// inclusive scan of counts (deg+1) in chunks of 1024
__global__ __launch_bounds__(1024) void scan1_kernel(const int* __restrict__ deg,
                                                     int* __restrict__ incl,
                                                     int* __restrict__ bsum) {
  __shared__ int sd[1024];
  int gid = blockIdx.x * 1024 + threadIdx.x;
  int v = (gid < NN) ? (deg[gid] + 1) : 0;
  sd[threadIdx.x] = v;
  __syncthreads();
  for (int off = 1; off < 1024; off <<= 1) {
    int t = (threadIdx.x >= off) ? sd[threadIdx.x - off] : 0;
    __syncthreads();
    sd[threadIdx.x] += t;
    __syncthreads();
  }
  if (gid < NN) incl[gid] = sd[threadIdx.x];
  if (threadIdx.x == 1023) bsum[blockIdx.x] = sd[1023];
}

__global__ void scan2_kernel(int* bsum, int nb) {
  if (threadIdx.x == 0 && blockIdx.x == 0) {
    int run = 0;
    for (int i = 0; i < nb; ++i) { int t = bsum[i]; bsum[i] = run; run += t; }
  }
}

__global__ void scan3_kernel(const int* __restrict__ deg, const int* __restrict__ incl,
                             const int* __restrict__ bsum, int* __restrict__ offs,
                             int* __restrict__ cursor) {
  int v = blockIdx.x * 256 + threadIdx.x;
  if (v >= NN) return;
  int o = bsum[v >> 10] + incl[v] - (deg[v] + 1);
  offs[v] = o;
  cursor[v] = o;
  if (v == 0) offs[NN] = NT;
}

// packed edge: .x = src node, .y = float bits of weight
__global__ void fill_kernel(const int* __restrict__ esrc, const int* __restrict__ edst,
                            const float* __restrict__ dinv, int* __restrict__ cursor,
                            int2* __restrict__ edges) {
  int i = blockIdx.x * 256 + threadIdx.x;
  if (i >= NT) return;
  int s, d;
  if (i < NE) { s = esrc[i]; d = edst[i]; }
  else        { s = d = i - NE; }           // self loop
  int p = atomicAdd(&cursor[d], 1);
  int2 e;
  e.x = s;
  e.y = __float_as_int(dinv[s] * dinv[d]);
  edges[p] = e;
}

// ---------------- dense GEMM: out = A[M,K] @ W[K,COLS] + bias ----------------
// 256 threads, tile 64 rows x COLS, K-chunk 32. Thread = 4 rows x CPT cols.
// tc = tid/16 -> ws reads are 16-lane broadcasts, conflict-free.
// xs stride 33 -> bank (4tr+r+k)%32 -> 2-way (free).

template <int K, int COLS>
__global__ __launch_bounds__(256) void gemm_bias_kernel(const float* __restrict__ A,
                                                        const float* __restrict__ W,
                                                        const float* __restrict__ bias,
                                                        float* __restrict__ out, int M) {
  constexpr int CPT = COLS / 16;  // 8 or 4
  __shared__ float xs[64][33];
  __shared__ float ws[32][COLS];

  int tid = threadIdx.x;
  int tc = tid >> 4;              // 0..15 col group
  int tr = tid & 15;              // 0..15 row group
  int row0 = blockIdx.x * 64;

  float acc[4][CPT] = {};

  for (int kc = 0; kc < K; kc += 32) {
    for (int i = tid; i < 512; i += 256) {
      int r = i >> 3, k4 = i & 7;
      int row = row0 + r;
      float4 v = make_float4(0.f, 0.f, 0.f, 0.f);
      if (row < M) v = *reinterpret_cast<const float4*>(&A[(size_t)row * K + kc + k4 * 4]);
      xs[r][k4 * 4 + 0] = v.x;
      xs[r][k4 * 4 + 1] = v.y;
      xs[r][k4 * 4 + 2] = v.z;
      xs[r][k4 * 4 + 3] = v.w;
    }
    for (int i = tid; i < 32 * COLS / 4; i += 256) {
      int k = i / (COLS / 4), c4 = i % (COLS / 4);
      *reinterpret_cast<float4*>(&ws[k][c4 * 4]) =
          *reinterpret_cast<const float4*>(&W[(size_t)(kc + k) * COLS + c4 * 4]);
    }
    __syncthreads();
#pragma unroll
    for (int k = 0; k < 32; ++k) {
      float xv[4];
#pragma unroll
      for (int r = 0; r < 4; ++r) xv[r] = xs[tr * 4 + r][k];
#pragma unroll
      for (int j4 = 0; j4 < CPT / 4; ++j4) {
        float4 wv = *reinterpret_cast<const float4*>(&ws[k][tc * CPT + j4 * 4]);
#pragma unroll
        for (int r = 0; r < 4; ++r) {
          acc[r][j4 * 4 + 0] += xv[r] * wv.x;
          acc[r][j4 * 4 + 1] += xv[r] * wv.y;
          acc[r][j4 * 4 + 2] += xv[r] * wv.z;
          acc[r][j4 * 4 + 3] += xv[r] * wv.w;
        }
      }
    }
    __syncthreads();
  }

#pragma unroll
  for (int r = 0; r < 4; ++r) {
    int row = row0 + tr * 4 + r;
    if (row < M) {
#pragma unroll
      for (int j4 = 0; j4 < CPT / 4; ++j4) {
        int c = tc * CPT + j4 * 4;
        float4 bv = *reinterpret_cast<const float4*>(&bias[c]);
        float4 o;
        o.x = acc[r][j4 * 4 + 0] + bv.x;
        o.y = acc[r][j4 * 4 + 1] + bv.y;
        o.z = acc[r][j4 * 4 + 2] + bv.z;
        o.w = acc[r][j4 * 4 + 3] + bv.w;
        *reinterpret_cast<float4*>(&out[(size_t)row * COLS + c]) = o;
      }
    }
  }
}

// ---------------- propagation: out[d] = sum_e w_e * h[src_e]  [*0.9 + 0.1 h0] ----
// F/4 threads per node, float4 gathers over full 512B rows (lines fully used).
// 8-deep edge unroll: 8 metadata dwordx2 + 8 gather dwordx4 in flight per lane.

template <int F, bool APPNP>
__global__ __launch_bounds__(256) void prop_kernel(const float* __restrict__ hin,
                                                   const float* __restrict__ h0,
                                                   float* __restrict__ out,
                                                   const int* __restrict__ offs,
                                                   const int2* __restrict__ edges) {
  constexpr int TPN = F / 4;        // 32 or 16
  constexpr int NPB = 256 / TPN;    // 8 or 16
  int node = blockIdx.x * NPB + threadIdx.x / TPN;
  if (node >= NN) return;
  int f = (threadIdx.x % TPN) * 4;
  const float* __restrict__ hb = hin + f;

  int e = offs[node];
  int e1 = offs[node + 1];
  float ax = 0.f, ay = 0.f, az = 0.f, aw = 0.f;

  for (; e + 7 < e1; e += 8) {
    int2 m[8];
#pragma unroll
    for (int j = 0; j < 8; ++j) m[j] = edges[e + j];
    float4 v[8];
#pragma unroll
    for (int j = 0; j < 8; ++j)
      v[j] = *reinterpret_cast<const float4*>(hb + (size_t)m[j].x * F);
#pragma unroll
    for (int j = 0; j < 8; ++j) {
      float wv = __int_as_float(m[j].y);
      ax += wv * v[j].x; ay += wv * v[j].y; az += wv * v[j].z; aw += wv * v[j].w;
    }
  }
  for (; e + 1 < e1; e += 2) {
    int2 m0 = edges[e], m1 = edges[e + 1];
    float4 v0 = *reinterpret_cast<const float4*>(hb + (size_t)m0.x * F);
    float4 v1 = *reinterpret_cast<const float4*>(hb + (size_t)m1.x * F);
    float w0 = __int_as_float(m0.y), w1 = __int_as_float(m1.y);
    ax += w0 * v0.x + w1 * v1.x;
    ay += w0 * v0.y + w1 * v1.y;
    az += w0 * v0.z + w1 * v1.z;
    aw += w0 * v0.w + w1 * v1.w;
  }
  if (e < e1) {
    int2 m = edges[e];
    float4 v = *reinterpret_cast<const float4*>(hb + (size_t)m.x * F);
    float wv = __int_as_float(m.y);
    ax += wv * v.x; ay += wv * v.y; az += wv * v.z; aw += wv * v.w;
  }

  if (APPNP) {
    float4 z = *reinterpret_cast<const float4*>(&h0[(size_t)node * F + f]);
    ax = 0.9f * ax + 0.1f * z.x;
    ay = 0.9f * ay + 0.1f * z.y;
    az = 0.9f * az + 0.1f * z.z;
    aw = 0.9f * aw + 0.1f * z.w;
  }
  float4 o = make_float4(ax, ay, az, aw);
  *reinterpret_cast<float4*>(&out[(size_t)node * F + f]) = o;
}

// ---------------- launch ----------------

extern "C" void kernel_launch(void* const* d_in, const int* in_sizes, int n_in,
                              void* d_out, int out_size, void* d_ws, size_t ws_size,
                              hipStream_t stream) {
  const float* x    = (const float*)d_in[0];   // [50000,256]
  const int*   eidx = (const int*)d_in[1];     // [2,800000]
  const float* W1   = (const float*)d_in[2];   // [256,128]
  const float* b1   = (const float*)d_in[3];   // [128]
  const float* W3   = (const float*)d_in[4];   // [128,64]
  const float* b3   = (const float*)d_in[5];   // [64]
  float* outp = (float*)d_out;                 // [50000,64]

  const int* esrc = eidx;
  const int* edst = eidx + NE;

  // workspace layout (256B aligned)
  char* w = (char*)d_ws;
  size_t off = 0;
  auto take = [&](size_t bytes) {
    void* p = w + off;
    off = (off + bytes + 255) & ~(size_t)255;
    return p;
  };
  int*   deg    = (int*)take(NN * 4);
  float* dinv   = (float*)take(NN * 4);
  int*   incl   = (int*)take(NN * 4);
  int*   offs   = (int*)take((NN + 1) * 4);
  int*   cursor = (int*)take(NN * 4);
  int*   bsum   = (int*)take(64 * 4);
  int2*  edges  = (int2*)take((size_t)NT * 8);
  float* h0b    = (float*)take((size_t)NN * 128 * 4);
  float* ping   = (float*)take((size_t)NN * 128 * 4);
  float* pong   = (float*)take((size_t)NN * 128 * 4);
  (void)ws_size; (void)in_sizes; (void)n_in; (void)out_size;

  const int nblkN = (NN + 255) / 256;          // 196
  const int nblkE = (NE + 255) / 256;          // 3125
  const int nblkT = (NT + 255) / 256;          // 3321
  const int nbScan = (NN + 1023) / 1024;       // 49

  // --- graph norm + CSR build ---
  zero_deg_kernel<<<nblkN, 256, 0, stream>>>(deg);
  count_deg_kernel<<<nblkE, 256, 0, stream>>>(edst, deg);
  dinv_kernel<<<nblkN, 256, 0, stream>>>(deg, dinv);
  scan1_kernel<<<nbScan, 1024, 0, stream>>>(deg, incl, bsum);
  scan2_kernel<<<1, 64, 0, stream>>>(bsum, nbScan);
  scan3_kernel<<<nblkN, 256, 0, stream>>>(deg, incl, bsum, offs, cursor);
  fill_kernel<<<nblkT, 256, 0, stream>>>(esrc, edst, dinv, cursor, edges);

  const int gblk = (NN + 63) / 64;             // 782

  // --- GCNConv1: h0 = prop(x @ W1 + b1) ---
  gemm_bias_kernel<256, 128><<<gblk, 256, 0, stream>>>(x, W1, b1, ping, NN);
  prop_kernel<128, false><<<(NN + 7) / 8, 256, 0, stream>>>(ping, nullptr, h0b, offs, edges);

  // --- APPNP: 10 x h = 0.9*prop(h) + 0.1*h0 ---
  const float* hc = h0b;
  float* bufs[2] = {ping, pong};
  for (int it = 0; it < 10; ++it) {
    float* hn = bufs[it & 1];
    prop_kernel<128, true><<<(NN + 7) / 8, 256, 0, stream>>>(hc, h0b, hn, offs, edges);
    hc = hn;
  }
  // hc == pong after 10 iters; ping is free
  float* t64 = ping;

  // --- GCNConv2: out = prop(h @ W3 + b3) ---
  gemm_bias_kernel<128, 64><<<gblk, 256, 0, stream>>>(hc, W3, b3, t64, NN);
  prop_kernel<64, false><<<(NN + 15) / 16, 256, 0, stream>>>(t64, nullptr, outp, offs, edges);
}

// Round 6
// 515.444 us; speedup vs baseline: 2.7753x; 1.7274x over previous
//
#include <hip/hip_runtime.h>

#define NN 50000          // nodes
#define NE 800000         // edges (without self loops)
#define NT (NE + NN)      // edges + self loops

// ---------------- graph preprocessing ----------------

__global__ void zero_deg_kernel(int* deg) {
  int v = blockIdx.x * 256 + threadIdx.x;
  if (v < NN) deg[v] = 0;
}

__global__ void count_deg_kernel(const int* __restrict__ edst, int* __restrict__ deg) {
  int i = blockIdx.x * 256 + threadIdx.x;
  if (i < NE) atomicAdd(&deg[edst[i]], 1);
}

__global__ void dinv_kernel(const int* __restrict__ deg, float* __restrict__ dinv) {
  int v = blockIdx.x * 256 + threadIdx.x;
  if (v < NN) dinv[v] = rsqrtf((float)(deg[v] + 1));   // +1 self loop
}

// inclusive scan of counts (deg+1) in chunks of 1024
__global__ __launch_bounds__(1024) void scan1_kernel(const int* __restrict__ deg,
                                                     int* __restrict__ incl,
                                                     int* __restrict__ bsum) {
  __shared__ int sd[1024];
  int gid = blockIdx.x * 1024 + threadIdx.x;
  int v = (gid < NN) ? (deg[gid] + 1) : 0;
  sd[threadIdx.x] = v;
  __syncthreads();
  for (int off = 1; off < 1024; off <<= 1) {
    int t = (threadIdx.x >= off) ? sd[threadIdx.x - off] : 0;
    __syncthreads();
    sd[threadIdx.x] += t;
    __syncthreads();
  }
  if (gid < NN) incl[gid] = sd[threadIdx.x];
  if (threadIdx.x == 1023) bsum[blockIdx.x] = sd[1023];
}

__global__ void scan2_kernel(int* bsum, int nb) {
  if (threadIdx.x == 0 && blockIdx.x == 0) {
    int run = 0;
    for (int i = 0; i < nb; ++i) { int t = bsum[i]; bsum[i] = run; run += t; }
  }
}

__global__ void scan3_kernel(const int* __restrict__ deg, const int* __restrict__ incl,
                             const int* __restrict__ bsum, int* __restrict__ offs,
                             int* __restrict__ cursor) {
  int v = blockIdx.x * 256 + threadIdx.x;
  if (v >= NN) return;
  int o = bsum[v >> 10] + incl[v] - (deg[v] + 1);
  offs[v] = o;
  cursor[v] = o;
  if (v == 0) offs[NN] = NT;
}

// packed edge: .x = src node, .y = float bits of weight
__global__ void fill_kernel(const int* __restrict__ esrc, const int* __restrict__ edst,
                            const float* __restrict__ dinv, int* __restrict__ cursor,
                            int2* __restrict__ edges) {
  int i = blockIdx.x * 256 + threadIdx.x;
  if (i >= NT) return;
  int s, d;
  if (i < NE) { s = esrc[i]; d = edst[i]; }
  else        { s = d = i - NE; }           // self loop
  int p = atomicAdd(&cursor[d], 1);
  int2 e;
  e.x = s;
  e.y = __float_as_int(dinv[s] * dinv[d]);
  edges[p] = e;
}

// rowsum[d] = sum of normalized edge weights into d (for the b3 bias term)
__global__ void rowsum_kernel(const int* __restrict__ offs, const int2* __restrict__ edges,
                              float* __restrict__ rowsum) {
  int v = blockIdx.x * 256 + threadIdx.x;
  if (v >= NN) return;
  float s = 0.f;
  int e1 = offs[v + 1];
  for (int e = offs[v]; e < e1; ++e) s += __int_as_float(edges[e].y);
  rowsum[v] = s;
}

// ---------------- tiny fused-weight prep: W13 = W1 @ W3, b13 = b1 @ W3 ------

__global__ void w13_kernel(const float* __restrict__ W1, const float* __restrict__ W3,
                           float* __restrict__ W13) {
  int idx = blockIdx.x * 256 + threadIdx.x;   // 256*64 outputs
  if (idx >= 256 * 64) return;
  int r = idx >> 6, c = idx & 63;
  float acc = 0.f;
  for (int k = 0; k < 128; ++k) acc += W1[r * 128 + k] * W3[k * 64 + c];
  W13[idx] = acc;
}

__global__ void b13_kernel(const float* __restrict__ b1, const float* __restrict__ W3,
                           float* __restrict__ b13) {
  int c = threadIdx.x;   // 64 threads
  if (c >= 64) return;
  float acc = 0.f;
  for (int k = 0; k < 128; ++k) acc += b1[k] * W3[k * 64 + c];
  b13[c] = acc;
}

// ---------------- dense GEMM: out[M,64] = A[M,K] @ W[K,64] + bias -----------
// 256 threads, tile 32 rows x 64 cols, K-chunk 32. Thread = 2 rows x 4 cols.
// tc = tid>>4 -> per-wave ws float4 reads hit 4 distinct bank groups, broadcast.
// xs stride 33 -> read bank (2tr+r+k)%32: 16 distinct banks, 4-lane broadcast.
// Grid = M/32 = 1563 blocks -> ~6 blocks/CU, LDS 12.3KB -> occupancy-friendly.

template <int K>
__global__ __launch_bounds__(256) void gemm64_kernel(const float* __restrict__ A,
                                                     const float* __restrict__ W,
                                                     const float* __restrict__ bias,
                                                     float* __restrict__ out, int M) {
  __shared__ float xs[32][33];
  __shared__ float ws[32][64];

  int tid = threadIdx.x;
  int tc = tid >> 4;              // 0..15 col group (4 cols each)
  int tr = tid & 15;              // 0..15 row group (2 rows each)
  int row0 = blockIdx.x * 32;

  float acc[2][4] = {};

  for (int kc = 0; kc < K; kc += 32) {
    // stage xs: 32 rows x 32 k = 256 float4, one per thread
    {
      int r = tid >> 3, k4 = tid & 7;
      int row = row0 + r;
      float4 v = make_float4(0.f, 0.f, 0.f, 0.f);
      if (row < M) v = *reinterpret_cast<const float4*>(&A[(size_t)row * K + kc + k4 * 4]);
      xs[r][k4 * 4 + 0] = v.x;
      xs[r][k4 * 4 + 1] = v.y;
      xs[r][k4 * 4 + 2] = v.z;
      xs[r][k4 * 4 + 3] = v.w;
    }
    // stage ws: 32 k x 64 c = 512 float4, two per thread
    for (int i = tid; i < 512; i += 256) {
      int k = i >> 4, c4 = i & 15;
      *reinterpret_cast<float4*>(&ws[k][c4 * 4]) =
          *reinterpret_cast<const float4*>(&W[(size_t)(kc + k) * 64 + c4 * 4]);
    }
    __syncthreads();
#pragma unroll
    for (int k = 0; k < 32; ++k) {
      float x0 = xs[tr * 2 + 0][k];
      float x1 = xs[tr * 2 + 1][k];
      float4 wv = *reinterpret_cast<const float4*>(&ws[k][tc * 4]);
      acc[0][0] += x0 * wv.x; acc[0][1] += x0 * wv.y;
      acc[0][2] += x0 * wv.z; acc[0][3] += x0 * wv.w;
      acc[1][0] += x1 * wv.x; acc[1][1] += x1 * wv.y;
      acc[1][2] += x1 * wv.z; acc[1][3] += x1 * wv.w;
    }
    __syncthreads();
  }

  float4 bv = *reinterpret_cast<const float4*>(&bias[tc * 4]);
#pragma unroll
  for (int r = 0; r < 2; ++r) {
    int row = row0 + tr * 2 + r;
    if (row < M) {
      float4 o;
      o.x = acc[r][0] + bv.x;
      o.y = acc[r][1] + bv.y;
      o.z = acc[r][2] + bv.z;
      o.w = acc[r][3] + bv.w;
      *reinterpret_cast<float4*>(&out[(size_t)row * 64 + tc * 4]) = o;
    }
  }
}

// ---------------- propagation (F=64): out[d] = sum_e w_e * h[src_e] --------
// MODE 0: plain   MODE 1: APPNP (0.9*acc + 0.1*h0)   MODE 2: final (+rowsum*b3)
// 16 threads/node, float4 gathers over full 256B rows; 8-deep edge unroll.

template <int MODE>
__global__ __launch_bounds__(256) void prop64_kernel(const float* __restrict__ hin,
                                                     const float* __restrict__ h0,
                                                     float* __restrict__ out,
                                                     const int* __restrict__ offs,
                                                     const int2* __restrict__ edges,
                                                     const float* __restrict__ rowsum,
                                                     const float* __restrict__ b3) {
  int node = blockIdx.x * 16 + (threadIdx.x >> 4);
  if (node >= NN) return;
  int f = (threadIdx.x & 15) * 4;
  const float* __restrict__ hb = hin + f;

  int e = offs[node];
  int e1 = offs[node + 1];
  float ax = 0.f, ay = 0.f, az = 0.f, aw = 0.f;

  for (; e + 7 < e1; e += 8) {
    int2 m[8];
#pragma unroll
    for (int j = 0; j < 8; ++j) m[j] = edges[e + j];
    float4 v[8];
#pragma unroll
    for (int j = 0; j < 8; ++j)
      v[j] = *reinterpret_cast<const float4*>(hb + (size_t)m[j].x * 64);
#pragma unroll
    for (int j = 0; j < 8; ++j) {
      float wv = __int_as_float(m[j].y);
      ax += wv * v[j].x; ay += wv * v[j].y; az += wv * v[j].z; aw += wv * v[j].w;
    }
  }
  for (; e + 1 < e1; e += 2) {
    int2 m0 = edges[e], m1 = edges[e + 1];
    float4 v0 = *reinterpret_cast<const float4*>(hb + (size_t)m0.x * 64);
    float4 v1 = *reinterpret_cast<const float4*>(hb + (size_t)m1.x * 64);
    float w0 = __int_as_float(m0.y), w1 = __int_as_float(m1.y);
    ax += w0 * v0.x + w1 * v1.x;
    ay += w0 * v0.y + w1 * v1.y;
    az += w0 * v0.z + w1 * v1.z;
    aw += w0 * v0.w + w1 * v1.w;
  }
  if (e < e1) {
    int2 m = edges[e];
    float4 v = *reinterpret_cast<const float4*>(hb + (size_t)m.x * 64);
    float wv = __int_as_float(m.y);
    ax += wv * v.x; ay += wv * v.y; az += wv * v.z; aw += wv * v.w;
  }

  if (MODE == 1) {
    float4 z = *reinterpret_cast<const float4*>(&h0[(size_t)node * 64 + f]);
    ax = 0.9f * ax + 0.1f * z.x;
    ay = 0.9f * ay + 0.1f * z.y;
    az = 0.9f * az + 0.1f * z.z;
    aw = 0.9f * aw + 0.1f * z.w;
  }
  if (MODE == 2) {
    float rs = rowsum[node];
    float4 bz = *reinterpret_cast<const float4*>(&b3[f]);
    ax += rs * bz.x; ay += rs * bz.y; az += rs * bz.z; aw += rs * bz.w;
  }
  float4 o = make_float4(ax, ay, az, aw);
  *reinterpret_cast<float4*>(&out[(size_t)node * 64 + f]) = o;
}

// ---------------- launch ----------------

extern "C" void kernel_launch(void* const* d_in, const int* in_sizes, int n_in,
                              void* d_out, int out_size, void* d_ws, size_t ws_size,
                              hipStream_t stream) {
  const float* x    = (const float*)d_in[0];   // [50000,256]
  const int*   eidx = (const int*)d_in[1];     // [2,800000]
  const float* W1   = (const float*)d_in[2];   // [256,128]
  const float* b1   = (const float*)d_in[3];   // [128]
  const float* W3   = (const float*)d_in[4];   // [128,64]
  const float* b3   = (const float*)d_in[5];   // [64]
  float* outp = (float*)d_out;                 // [50000,64]

  const int* esrc = eidx;
  const int* edst = eidx + NE;

  // workspace layout (256B aligned)
  char* w = (char*)d_ws;
  size_t off = 0;
  auto take = [&](size_t bytes) {
    void* p = w + off;
    off = (off + bytes + 255) & ~(size_t)255;
    return p;
  };
  int*   deg    = (int*)take(NN * 4);
  float* dinv   = (float*)take(NN * 4);
  int*   incl   = (int*)take(NN * 4);
  int*   offs   = (int*)take((NN + 1) * 4);
  int*   cursor = (int*)take(NN * 4);
  int*   bsum   = (int*)take(64 * 4);
  float* rsum   = (float*)take(NN * 4);
  float* W13    = (float*)take(256 * 64 * 4);
  float* b13    = (float*)take(64 * 4);
  int2*  edges  = (int2*)take((size_t)NT * 8);
  float* y0     = (float*)take((size_t)NN * 64 * 4);
  float* z0     = (float*)take((size_t)NN * 64 * 4);
  float* zp     = (float*)take((size_t)NN * 64 * 4);
  float* zq     = (float*)take((size_t)NN * 64 * 4);
  (void)ws_size; (void)in_sizes; (void)n_in; (void)out_size;

  const int nblkN = (NN + 255) / 256;          // 196
  const int nblkE = (NE + 255) / 256;          // 3125
  const int nblkT = (NT + 255) / 256;          // 3321
  const int nbScan = (NN + 1023) / 1024;       // 49

  // --- fused weights (independent of graph) ---
  w13_kernel<<<64, 256, 0, stream>>>(W1, W3, W13);
  b13_kernel<<<1, 64, 0, stream>>>(b1, W3, b13);

  // --- graph norm + CSR build ---
  zero_deg_kernel<<<nblkN, 256, 0, stream>>>(deg);
  count_deg_kernel<<<nblkE, 256, 0, stream>>>(edst, deg);
  dinv_kernel<<<nblkN, 256, 0, stream>>>(deg, dinv);
  scan1_kernel<<<nbScan, 1024, 0, stream>>>(deg, incl, bsum);
  scan2_kernel<<<1, 64, 0, stream>>>(bsum, nbScan);
  scan3_kernel<<<nblkN, 256, 0, stream>>>(deg, incl, bsum, offs, cursor);
  fill_kernel<<<nblkT, 256, 0, stream>>>(esrc, edst, dinv, cursor, edges);
  rowsum_kernel<<<nblkN, 256, 0, stream>>>(offs, edges, rsum);

  // --- y0 = x @ W13 + b13 ---
  gemm64_kernel<256><<<(NN + 31) / 32, 256, 0, stream>>>(x, W13, b13, y0, NN);

  const int pblk = (NN + 15) / 16;             // 3125

  // --- z0 = A_hat y0  (this is h0 @ W3) ---
  prop64_kernel<0><<<pblk, 256, 0, stream>>>(y0, nullptr, z0, offs, edges, nullptr, nullptr);

  // --- APPNP in 64-dim: 10 x z = 0.9 A_hat z + 0.1 z0 ---
  const float* hc = z0;
  float* bufs[2] = {zp, zq};
  for (int it = 0; it < 10; ++it) {
    float* hn = bufs[it & 1];
    prop64_kernel<1><<<pblk, 256, 0, stream>>>(hc, z0, hn, offs, edges, nullptr, nullptr);
    hc = hn;
  }

  // --- out = A_hat z + rowsum * b3 ---
  prop64_kernel<2><<<pblk, 256, 0, stream>>>(hc, nullptr, outp, offs, edges, rsum, b3);
}